// Round 18
// baseline (125.326 us; speedup 1.0000x reference)
//
#include <hip/hip_runtime.h>

#define NB   16
#define CD   256
#define HWD  4096

typedef __attribute__((ext_vector_type(8))) short short8;
typedef __attribute__((ext_vector_type(4))) float f32x4;

static __device__ __forceinline__ float b2f(unsigned short u) {
  union { unsigned int i; float f; } x; x.i = ((unsigned int)u) << 16; return x.f;
}
static __device__ __forceinline__ unsigned short f2b(float f) {
  union { float f; unsigned int i; } x; x.f = f;
  return (unsigned short)((x.i + 0x7fffu + ((x.i >> 16) & 1u)) >> 16);
}

static __device__ __forceinline__ void gload16(const void* g, const unsigned short* l) {
  __builtin_amdgcn_global_load_lds(
      (const __attribute__((address_space(1))) void*)g,
      (__attribute__((address_space(3))) void*)l, 16, 0, 0);
}

// ---------------------------------------------------------------------------
// prep: Wk|Wq|Wv (each 256x256 f32) -> Wc bf16 [768][256]
// ---------------------------------------------------------------------------
__global__ __launch_bounds__(256)
void prep_kernel(const float* __restrict__ Wk, const float* __restrict__ Wq,
                 const float* __restrict__ Wv, unsigned short* __restrict__ Wc)
{
  int e4 = blockIdx.x * 256 + threadIdx.x;
  int base = e4 * 4;
  int w = base >> 16, off = base & 65535;
  const float* W = (w == 0) ? Wk : (w == 1) ? Wq : Wv;
  f32x4 v = *(const f32x4*)(W + off);
  unsigned int lo = (unsigned int)f2b(v.x) | ((unsigned int)f2b(v.y) << 16);
  unsigned int hi = (unsigned int)f2b(v.z) | ((unsigned int)f2b(v.w) << 16);
  *(uint2*)(Wc + base) = make_uint2(lo, hi);
}

// ---------------------------------------------------------------------------
// xT: x [n][256][4096] f32 -> xT [n][4096][256] bf16  (tile transpose)
// ---------------------------------------------------------------------------
__global__ __launch_bounds__(256)
void xt_kernel(const float* __restrict__ x, unsigned short* __restrict__ xT)
{
  __shared__ __align__(16) unsigned short T[64 * 80];
  const int t = threadIdx.x;
  const int l0 = blockIdx.x * 64, c0 = blockIdx.y * 64, n = blockIdx.z;
  const float* xn = x + (size_t)n * CD * HWD;
#pragma unroll
  for (int i = 0; i < 4; ++i) {
    int idx = t + i * 256;
    int c = idx >> 4, l4 = (idx & 15) * 4;
    f32x4 v = *(const f32x4*)(xn + (size_t)(c0 + c) * HWD + l0 + l4);
    T[(l4 + 0) * 80 + c] = f2b(v.x);
    T[(l4 + 1) * 80 + c] = f2b(v.y);
    T[(l4 + 2) * 80 + c] = f2b(v.z);
    T[(l4 + 3) * 80 + c] = f2b(v.w);
  }
  __syncthreads();
  unsigned short* dst = xT + ((size_t)n * HWD + l0) * CD + c0;
#pragma unroll
  for (int i = 0; i < 2; ++i) {
    int e = t + i * 256;
    int lr = e >> 3, c8 = (e & 7) * 8;
    *(short8*)(dst + (size_t)lr * CD + c8) = *(const short8*)(T + lr * 80 + c8);
  }
}

// ---------------------------------------------------------------------------
// kqv: 128x128 tile, BK=32 dbuf (NBUF=2), depth-2 counted-vmcnt pipeline
// (R11/R13-verified). Keys stored as exp(keys+bias) + per-row partial sums
// (from the Co LDS buffer, AFTER acc is dead) to stats2d[32][4096].
// Queries: in-register head-group(32) softmax, stored TRANSPOSED qsmT[l][c].
// (R17 verbatim)
// ---------------------------------------------------------------------------
__global__ __launch_bounds__(256, 4)
void kqv_kernel(const unsigned short* __restrict__ Wc,
                const unsigned short* __restrict__ xT,
                const float* __restrict__ bk, const float* __restrict__ bq,
                const float* __restrict__ bv,
                unsigned short* __restrict__ ekeys,
                unsigned short* __restrict__ qsmT,
                unsigned short* __restrict__ vals,
                float* __restrict__ stats2d)
{
  __shared__ __align__(16) unsigned short smem[17408];

  const int t  = threadIdx.x;
  const int lt = blockIdx.x;        // 0..31
  const int mt = blockIdx.y;        // 0..5
  const int n  = blockIdx.z;
  const int l0 = lt * 128;
  const int m0 = mt * 128;
  const int wsel = m0 >> 8;         // 0 keys, 1 queries, 2 values
  const int ocbase = m0 & 255;

  const unsigned short* Ag  = Wc;
  const unsigned short* Btn = xT + (size_t)n * HWD * CD;

  const int w = t >> 6, lane = t & 63;
  const int wr = (w >> 1) * 64, wc = (w & 1) * 64;
  const int lhi = lane >> 4, llo = lane & 15;

  f32x4 acc[4][4] = {};

  auto stage = [&](int buf, int ks) {
    unsigned short* As = smem + buf * 8192;
    unsigned short* Bs = As + 4096;
    const int k0 = ks * 32;
#pragma unroll
    for (int i = 0; i < 2; ++i) {
      int s   = t + i * 256;
      int row = s >> 2;
      int src = (((s ^ row) & 3)) << 3;
      gload16(Ag  + (size_t)(m0 + row) * CD + k0 + src, As + s * 8);
      gload16(Btn + (size_t)(l0 + row) * CD + k0 + src, Bs + s * 8);
    }
  };

  stage(0, 0);
  stage(1, 1);                      // 8 loads outstanding
#pragma unroll
  for (int ks = 0; ks < 8; ++ks) {
    if (ks < 7) asm volatile("s_waitcnt vmcnt(4)" ::: "memory");
    else        asm volatile("s_waitcnt vmcnt(0)" ::: "memory");
    asm volatile("s_barrier" ::: "memory");        // cur buf landed everywhere

    const unsigned short* As = smem + (ks & 1) * 8192;
    const unsigned short* Bs = As + 4096;
    const int slot = (lhi ^ (llo & 3)) * 8;
    short8 a[4], b[4];
#pragma unroll
    for (int mi = 0; mi < 4; ++mi)
      a[mi] = *(const short8*)(As + (wr + mi * 16 + llo) * 32 + slot);
#pragma unroll
    for (int ni = 0; ni < 4; ++ni)
      b[ni] = *(const short8*)(Bs + (wc + ni * 16 + llo) * 32 + slot);

    asm volatile("s_waitcnt lgkmcnt(0)" ::: "memory");  // reads complete
    asm volatile("s_barrier" ::: "memory");             // all waves done reading

    if (ks < 6) stage(ks & 1, ks + 2);   // overwrite cur; back to 8 in flight

#pragma unroll
    for (int mi = 0; mi < 4; ++mi)
#pragma unroll
      for (int ni = 0; ni < 4; ++ni)
        acc[mi][ni] = __builtin_amdgcn_mfma_f32_16x16x32_bf16(a[mi], b[ni], acc[mi][ni], 0, 0, 0);
  }

  const float* bias = (wsel == 0) ? bk : (wsel == 1) ? bq : bv;

  if (wsel == 1) {
#pragma unroll
    for (int mi = 0; mi < 4; ++mi)
#pragma unroll
      for (int r = 0; r < 4; ++r) {
        float bb = bias[ocbase + wr + mi * 16 + lhi * 4 + r];
#pragma unroll
        for (int ni = 0; ni < 4; ++ni) acc[mi][ni][r] += bb;
      }
#pragma unroll
    for (int g = 0; g < 2; ++g) {
#pragma unroll
      for (int ni = 0; ni < 4; ++ni) {
        float m = -1e30f;
#pragma unroll
        for (int mi = 2 * g; mi < 2 * g + 2; ++mi)
#pragma unroll
          for (int r = 0; r < 4; ++r) m = fmaxf(m, acc[mi][ni][r]);
        m = fmaxf(m, __shfl_xor(m, 16));
        m = fmaxf(m, __shfl_xor(m, 32));
        float s = 0.f;
#pragma unroll
        for (int mi = 2 * g; mi < 2 * g + 2; ++mi)
#pragma unroll
          for (int r = 0; r < 4; ++r) {
            float e = __expf(acc[mi][ni][r] - m);
            acc[mi][ni][r] = e;
            s += e;
          }
        s += __shfl_xor(s, 16);
        s += __shfl_xor(s, 32);
        float inv = 1.f / s;
#pragma unroll
        for (int mi = 2 * g; mi < 2 * g + 2; ++mi)
#pragma unroll
          for (int r = 0; r < 4; ++r) acc[mi][ni][r] *= inv;
      }
    }
    unsigned short* Co2 = smem;
#pragma unroll
    for (int mi = 0; mi < 4; ++mi)
#pragma unroll
      for (int ni = 0; ni < 4; ++ni) {
        int col = wc + ni * 16 + llo;
#pragma unroll
        for (int r = 0; r < 4; ++r) {
          int row = wr + mi * 16 + lhi * 4 + r;
          Co2[col * 136 + row] = f2b(acc[mi][ni][r]);
        }
      }
    __syncthreads();
    unsigned short* dst = qsmT + ((size_t)n * HWD + l0) * CD + ocbase;
#pragma unroll
    for (int i = 0; i < 8; ++i) {
      int e = t + i * 256;
      int l = e >> 4, c8 = (e & 15) * 8;
      *(short8*)(dst + (size_t)l * CD + c8) = *(const short8*)(Co2 + l * 136 + c8);
    }
  } else {
    // keys: store exp(k+bias); values: store k+bias.
    unsigned short* Co = smem;
#pragma unroll
    for (int mi = 0; mi < 4; ++mi)
#pragma unroll
      for (int ni = 0; ni < 4; ++ni) {
        int col = wc + ni * 16 + llo;
#pragma unroll
        for (int r = 0; r < 4; ++r) {
          int row = wr + mi * 16 + lhi * 4 + r;
          float val = acc[mi][ni][r] + bias[ocbase + row];
          if (wsel == 0) val = __expf(val);
          Co[row * 136 + col] = f2b(val);
        }
      }
    __syncthreads();
    unsigned short* dst = ((wsel == 0) ? ekeys : vals)
                          + ((size_t)(n * CD + ocbase)) * HWD + l0;
#pragma unroll
    for (int i = 0; i < 8; ++i) {
      int e = t + i * 256;
      int row = e >> 4, c8 = (e & 15) * 8;
      *(short8*)(dst + (size_t)row * HWD + c8) = *(const short8*)(Co + row * 136 + c8);
    }

    if (wsel == 0) {
      // ---- per-row partial sums from Co (acc dead; reads only) ----
      int row = t >> 1, half = t & 1;
      float s = 0.f;
#pragma unroll
      for (int j = 0; j < 8; ++j) {
        const short8 u = *(const short8*)(Co + row * 136 + half * 64 + j * 8);
#pragma unroll
        for (int k = 0; k < 8; ++k) s += b2f((unsigned short)u[k]);
      }
      s += __shfl_xor(s, 1);
      if (!half) stats2d[(size_t)lt * 4096 + n * CD + ocbase + row] = s;
    }
  }
}

// ---------------------------------------------------------------------------
// ctx partials: 8-way spatial split (1024 blocks, 4/CU). UNNORMALIZED
// E @ V^T, pure streaming; 1/rowsum applied in proj.
// ---------------------------------------------------------------------------
__global__ __launch_bounds__(256)
void ctx_kernel(const unsigned short* __restrict__ ekeys,
                const unsigned short* __restrict__ vals,
                float* __restrict__ ctxp)       // [8][128][32][32]
{
  __shared__ float Cs[4][32][33];
  const int hf = blockIdx.x;          // 0..7
  const int nh = blockIdx.y;          // 0..127
  const int n = nh >> 3, h = nh & 7;
  const int t = threadIdx.x, w = t >> 6, lane = t & 63;
  const int lhi = lane >> 4, llo = lane & 15;
  const int lbase = hf * 512 + w * 128;

  const unsigned short* kr = ekeys + (size_t)(n * CD + h * 32) * HWD;
  const unsigned short* vr = vals + (size_t)(n * CD + h * 32) * HWD;

  f32x4 acc[2][2] = {};
#pragma unroll
  for (int ks = 0; ks < 4; ++ks) {
    const int loff = lbase + ks * 32 + lhi * 8;
    short8 a[2], b[2];
#pragma unroll
    for (int mi = 0; mi < 2; ++mi)
      a[mi] = *(const short8*)(kr + (size_t)(mi * 16 + llo) * HWD + loff);
#pragma unroll
    for (int ni = 0; ni < 2; ++ni)
      b[ni] = *(const short8*)(vr + (size_t)(ni * 16 + llo) * HWD + loff);
    acc[0][0] = __builtin_amdgcn_mfma_f32_16x16x32_bf16(a[0], b[0], acc[0][0], 0, 0, 0);
    acc[0][1] = __builtin_amdgcn_mfma_f32_16x16x32_bf16(a[0], b[1], acc[0][1], 0, 0, 0);
    acc[1][0] = __builtin_amdgcn_mfma_f32_16x16x32_bf16(a[1], b[0], acc[1][0], 0, 0, 0);
    acc[1][1] = __builtin_amdgcn_mfma_f32_16x16x32_bf16(a[1], b[1], acc[1][1], 0, 0, 0);
  }

#pragma unroll
  for (int mi = 0; mi < 2; ++mi)
#pragma unroll
    for (int ni = 0; ni < 2; ++ni)
#pragma unroll
      for (int r = 0; r < 4; ++r)
        Cs[w][mi * 16 + lhi * 4 + r][ni * 16 + llo] = acc[mi][ni][r];
  __syncthreads();
#pragma unroll
  for (int i = 0; i < 4; ++i) {
    int e = t + i * 256;
    int kc = e >> 5, vc = e & 31;
    float sum = Cs[0][kc][vc] + Cs[1][kc][vc] + Cs[2][kc][vc] + Cs[3][kc][vc];
    ctxp[((size_t)hf * 128 + nh) * 1024 + e] = sum;
  }
}

// ---------------------------------------------------------------------------
// proj: sums 8 ctx partials, applies inv[kc] = 1/(sum of 32 stats2d
// partials), then M_n[o][h*32+kc] = sum_vc Wr[o][h*32+vc]*ctx[kc][vc], bf16.
// ---------------------------------------------------------------------------
__global__ __launch_bounds__(256)
void proj_kernel(const float* __restrict__ ctxp, const float* __restrict__ Wr,
                 const float* __restrict__ stats2d,
                 unsigned short* __restrict__ M)
{
  __shared__ float cs[32][33];
  __shared__ float invs[32];
  const int nh = blockIdx.x;
  const int n = nh >> 3, h = nh & 7;
  const int t = threadIdx.x;

  if (t < 32) {
    int grow = n * CD + h * 32 + t;
    float s = 0.f;
#pragma unroll
    for (int p = 0; p < 32; ++p) s += stats2d[(size_t)p * 4096 + grow];
    invs[t] = 1.f / s;
  }
  __syncthreads();

#pragma unroll
  for (int i = 0; i < 4; ++i) {
    int e = t + i * 256;
    float s = 0.f;
#pragma unroll
    for (int p = 0; p < 8; ++p)
      s += ctxp[((size_t)p * 128 + nh) * 1024 + e];
    cs[e >> 5][e & 31] = s * invs[e >> 5];
  }
  __syncthreads();
  float wreg[32];
  const float* wp = Wr + (size_t)t * 256 + h * 32;
#pragma unroll
  for (int i = 0; i < 8; ++i) {
    f32x4 v = *(const f32x4*)(wp + i * 4);
    wreg[i * 4] = v.x; wreg[i * 4 + 1] = v.y; wreg[i * 4 + 2] = v.z; wreg[i * 4 + 3] = v.w;
  }
  unsigned short o16[32];
#pragma unroll
  for (int kc = 0; kc < 32; ++kc) {
    float s = 0.f;
#pragma unroll
    for (int vv = 0; vv < 32; ++vv) s += wreg[vv] * cs[kc][vv];
    o16[kc] = f2b(s);
  }
  unsigned short* mp = M + (size_t)(n * CD + t) * 256 + h * 32;
#pragma unroll
  for (int i = 0; i < 8; ++i) {
    unsigned int lo = (unsigned int)o16[i * 4]     | ((unsigned int)o16[i * 4 + 1] << 16);
    unsigned int hi = (unsigned int)o16[i * 4 + 2] | ((unsigned int)o16[i * 4 + 3] << 16);
    *(uint2*)(mp + i * 4) = make_uint2(lo, hi);
  }
}

// ---------------------------------------------------------------------------
// out: 64x64 tile, BOTH panels (M rows, qsmT rows; K=256) LDS-resident via
// one gload16 stage; barrier-free K-loop (R13 verbatim). Epilogue: bias +
// residual, fp32 direct.
// ---------------------------------------------------------------------------
__global__ __launch_bounds__(256, 2)
void out_kernel(const unsigned short* __restrict__ M,
                const unsigned short* __restrict__ qsmT,
                const float* __restrict__ br,
                const float* __restrict__ x,
                float* __restrict__ out)
{
  __shared__ __align__(16) unsigned short smem[32768];  // As 64x256 | Bs 64x256
  unsigned short* As = smem;
  unsigned short* Bs = smem + 16384;

  const int t  = threadIdx.x;
  const int lt = blockIdx.x;        // 0..63
  const int mt = blockIdx.y;        // 0..3
  const int n  = blockIdx.z;
  const int l0 = lt * 64, m0 = mt * 64;

  const unsigned short* Ag  = M + (size_t)n * CD * 256;
  const unsigned short* Btn = qsmT + (size_t)n * HWD * CD;

  const int wid = t >> 6, lane = t & 63;
  const int wr = (wid >> 1) * 32, wc = (wid & 1) * 32;
  const int lhi = lane >> 4, llo = lane & 15;

#pragma unroll
  for (int i = 0; i < 8; ++i) {
    int s = t + i * 256;            // 0..2047
    int R = s >> 5, sl = s & 31;
    int srcsl = (sl & 24) | ((sl ^ R) & 7);
    gload16(Ag  + (size_t)(m0 + R) * CD + srcsl * 8, As + s * 8);
    gload16(Btn + (size_t)(l0 + R) * CD + srcsl * 8, Bs + s * 8);
  }
  __syncthreads();

  f32x4 acc[2][2] = {};
#pragma unroll
  for (int ks = 0; ks < 8; ++ks) {
    int jg = ks * 4 + lhi;          // k-slot 0..31
    short8 a[2], b[2];
#pragma unroll
    for (int mi = 0; mi < 2; ++mi) {
      int R = wr + mi * 16 + llo;
      int pj = (jg & 24) | ((jg ^ (R & 7)) & 7);
      a[mi] = *(const short8*)(As + R * 256 + pj * 8);
    }
#pragma unroll
    for (int ni = 0; ni < 2; ++ni) {
      int l = wc + ni * 16 + llo;
      int pj = (jg & 24) | ((jg ^ (l & 7)) & 7);
      b[ni] = *(const short8*)(Bs + l * 256 + pj * 8);
    }
#pragma unroll
    for (int mi = 0; mi < 2; ++mi)
#pragma unroll
      for (int ni = 0; ni < 2; ++ni)
        acc[mi][ni] = __builtin_amdgcn_mfma_f32_16x16x32_bf16(a[mi], b[ni], acc[mi][ni], 0, 0, 0);
  }

  const float* xn = x + (size_t)n * CD * HWD;
  float* on = out + (size_t)n * CD * HWD;
#pragma unroll
  for (int mi = 0; mi < 2; ++mi)
#pragma unroll
    for (int r = 0; r < 4; ++r) {
      int row = m0 + wr + mi * 16 + lhi * 4 + r;
      float bb = br[row];
#pragma unroll
      for (int ni = 0; ni < 2; ++ni) {
        int col = l0 + wc + ni * 16 + llo;
        size_t off = (size_t)row * HWD + col;
        on[off] = acc[mi][ni][r] + bb + xn[off];
      }
    }
}

// ---------------------------------------------------------------------------
extern "C" void kernel_launch(void* const* d_in, const int* in_sizes, int n_in,
                              void* d_out, int out_size, void* d_ws, size_t ws_size,
                              hipStream_t stream) {
  const float* x  = (const float*)d_in[0];
  const float* Wk = (const float*)d_in[1];
  const float* bk = (const float*)d_in[2];
  const float* Wq = (const float*)d_in[3];
  const float* bq = (const float*)d_in[4];
  const float* Wv = (const float*)d_in[5];
  const float* bv = (const float*)d_in[6];
  const float* Wr = (const float*)d_in[7];
  const float* br = (const float*)d_in[8];
  float* out = (float*)d_out;

  char* ws = (char*)d_ws;
  // ws layout (bytes): ekeys 32M | vals 32M | qsmT 32M | stats2d 512K | M 2M | Wc 384K
  unsigned short* ekeys = (unsigned short*)(ws);
  unsigned short* vals  = (unsigned short*)(ws + 33554432);
  unsigned short* qsmT  = (unsigned short*)(ws + 67108864);
  float* stats2d        = (float*)(ws + 100663296);
  unsigned short* M     = (unsigned short*)(ws + 101744640);
  unsigned short* Wc    = (unsigned short*)(ws + 103841792);
  // d_out scratch: xT bf16 (32MB) at offset 0 (dead before out_kernel writes),
  // ctx partials f32 [8][128][1024] (4MB) at +32MB (consumed by proj first).
  unsigned short* xT    = (unsigned short*)d_out;
  float* ctxp           = (float*)((char*)d_out + 33554432);

  hipLaunchKernelGGL(prep_kernel, dim3(192), dim3(256), 0, stream, Wk, Wq, Wv, Wc);
  hipLaunchKernelGGL(xt_kernel, dim3(64, 4, NB), dim3(256), 0, stream, x, xT);
  hipLaunchKernelGGL(kqv_kernel, dim3(32, 6, NB), dim3(256), 0, stream,
                     Wc, xT, bk, bq, bv, ekeys, qsmT, vals, stats2d);
  hipLaunchKernelGGL(ctx_kernel, dim3(8, 128), dim3(256), 0, stream,
                     ekeys, vals, ctxp);
  hipLaunchKernelGGL(proj_kernel, dim3(128), dim3(256), 0, stream,
                     ctxp, Wr, stats2d, M);
  hipLaunchKernelGGL(out_kernel, dim3(64, 4, NB), dim3(256), 0, stream,
                     M, qsmT, br, x, out);
}

// Round 19
// 125.146 us; speedup vs baseline: 1.0014x; 1.0014x over previous
//
#include <hip/hip_runtime.h>

#define NB   16
#define CD   256
#define HWD  4096

typedef __attribute__((ext_vector_type(8))) short short8;
typedef __attribute__((ext_vector_type(4))) float f32x4;

static __device__ __forceinline__ float b2f(unsigned short u) {
  union { unsigned int i; float f; } x; x.i = ((unsigned int)u) << 16; return x.f;
}
static __device__ __forceinline__ unsigned short f2b(float f) {
  union { float f; unsigned int i; } x; x.f = f;
  return (unsigned short)((x.i + 0x7fffu + ((x.i >> 16) & 1u)) >> 16);
}

static __device__ __forceinline__ void gload16(const void* g, const unsigned short* l) {
  __builtin_amdgcn_global_load_lds(
      (const __attribute__((address_space(1))) void*)g,
      (__attribute__((address_space(3))) void*)l, 16, 0, 0);
}

// ---------------------------------------------------------------------------
// prep: Wk|Wq|Wv (each 256x256 f32) -> Wc bf16 [768][256]
// ---------------------------------------------------------------------------
__global__ __launch_bounds__(256)
void prep_kernel(const float* __restrict__ Wk, const float* __restrict__ Wq,
                 const float* __restrict__ Wv, unsigned short* __restrict__ Wc)
{
  int e4 = blockIdx.x * 256 + threadIdx.x;
  int base = e4 * 4;
  int w = base >> 16, off = base & 65535;
  const float* W = (w == 0) ? Wk : (w == 1) ? Wq : Wv;
  f32x4 v = *(const f32x4*)(W + off);
  unsigned int lo = (unsigned int)f2b(v.x) | ((unsigned int)f2b(v.y) << 16);
  unsigned int hi = (unsigned int)f2b(v.z) | ((unsigned int)f2b(v.w) << 16);
  *(uint2*)(Wc + base) = make_uint2(lo, hi);
}

// ---------------------------------------------------------------------------
// xT: x [n][256][4096] f32 -> xT [n][4096][256] bf16  (tile transpose)
// ---------------------------------------------------------------------------
__global__ __launch_bounds__(256)
void xt_kernel(const float* __restrict__ x, unsigned short* __restrict__ xT)
{
  __shared__ __align__(16) unsigned short T[64 * 80];
  const int t = threadIdx.x;
  const int l0 = blockIdx.x * 64, c0 = blockIdx.y * 64, n = blockIdx.z;
  const float* xn = x + (size_t)n * CD * HWD;
#pragma unroll
  for (int i = 0; i < 4; ++i) {
    int idx = t + i * 256;
    int c = idx >> 4, l4 = (idx & 15) * 4;
    f32x4 v = *(const f32x4*)(xn + (size_t)(c0 + c) * HWD + l0 + l4);
    T[(l4 + 0) * 80 + c] = f2b(v.x);
    T[(l4 + 1) * 80 + c] = f2b(v.y);
    T[(l4 + 2) * 80 + c] = f2b(v.z);
    T[(l4 + 3) * 80 + c] = f2b(v.w);
  }
  __syncthreads();
  unsigned short* dst = xT + ((size_t)n * HWD + l0) * CD + c0;
#pragma unroll
  for (int i = 0; i < 2; ++i) {
    int e = t + i * 256;
    int lr = e >> 3, c8 = (e & 7) * 8;
    *(short8*)(dst + (size_t)lr * CD + c8) = *(const short8*)(T + lr * 80 + c8);
  }
}

// ---------------------------------------------------------------------------
// kqv: 128x128 tile, BK=32 dbuf (NBUF=2), depth-2 counted-vmcnt pipeline
// (R11/R13-verified). Keys stored as exp(keys+bias) + per-row partial sums
// (from the Co LDS buffer, AFTER acc is dead) to stats2d[32][4096].
// Queries: in-register head-group(32) softmax, stored TRANSPOSED qsmT[l][c].
// (R17 verbatim)
// ---------------------------------------------------------------------------
__global__ __launch_bounds__(256, 4)
void kqv_kernel(const unsigned short* __restrict__ Wc,
                const unsigned short* __restrict__ xT,
                const float* __restrict__ bk, const float* __restrict__ bq,
                const float* __restrict__ bv,
                unsigned short* __restrict__ ekeys,
                unsigned short* __restrict__ qsmT,
                unsigned short* __restrict__ vals,
                float* __restrict__ stats2d)
{
  __shared__ __align__(16) unsigned short smem[17408];

  const int t  = threadIdx.x;
  const int lt = blockIdx.x;        // 0..31
  const int mt = blockIdx.y;        // 0..5
  const int n  = blockIdx.z;
  const int l0 = lt * 128;
  const int m0 = mt * 128;
  const int wsel = m0 >> 8;         // 0 keys, 1 queries, 2 values
  const int ocbase = m0 & 255;

  const unsigned short* Ag  = Wc;
  const unsigned short* Btn = xT + (size_t)n * HWD * CD;

  const int w = t >> 6, lane = t & 63;
  const int wr = (w >> 1) * 64, wc = (w & 1) * 64;
  const int lhi = lane >> 4, llo = lane & 15;

  f32x4 acc[4][4] = {};

  auto stage = [&](int buf, int ks) {
    unsigned short* As = smem + buf * 8192;
    unsigned short* Bs = As + 4096;
    const int k0 = ks * 32;
#pragma unroll
    for (int i = 0; i < 2; ++i) {
      int s   = t + i * 256;
      int row = s >> 2;
      int src = (((s ^ row) & 3)) << 3;
      gload16(Ag  + (size_t)(m0 + row) * CD + k0 + src, As + s * 8);
      gload16(Btn + (size_t)(l0 + row) * CD + k0 + src, Bs + s * 8);
    }
  };

  stage(0, 0);
  stage(1, 1);                      // 8 loads outstanding
#pragma unroll
  for (int ks = 0; ks < 8; ++ks) {
    if (ks < 7) asm volatile("s_waitcnt vmcnt(4)" ::: "memory");
    else        asm volatile("s_waitcnt vmcnt(0)" ::: "memory");
    asm volatile("s_barrier" ::: "memory");        // cur buf landed everywhere

    const unsigned short* As = smem + (ks & 1) * 8192;
    const unsigned short* Bs = As + 4096;
    const int slot = (lhi ^ (llo & 3)) * 8;
    short8 a[4], b[4];
#pragma unroll
    for (int mi = 0; mi < 4; ++mi)
      a[mi] = *(const short8*)(As + (wr + mi * 16 + llo) * 32 + slot);
#pragma unroll
    for (int ni = 0; ni < 4; ++ni)
      b[ni] = *(const short8*)(Bs + (wc + ni * 16 + llo) * 32 + slot);

    asm volatile("s_waitcnt lgkmcnt(0)" ::: "memory");  // reads complete
    asm volatile("s_barrier" ::: "memory");             // all waves done reading

    if (ks < 6) stage(ks & 1, ks + 2);   // overwrite cur; back to 8 in flight

#pragma unroll
    for (int mi = 0; mi < 4; ++mi)
#pragma unroll
      for (int ni = 0; ni < 4; ++ni)
        acc[mi][ni] = __builtin_amdgcn_mfma_f32_16x16x32_bf16(a[mi], b[ni], acc[mi][ni], 0, 0, 0);
  }

  const float* bias = (wsel == 0) ? bk : (wsel == 1) ? bq : bv;

  if (wsel == 1) {
#pragma unroll
    for (int mi = 0; mi < 4; ++mi)
#pragma unroll
      for (int r = 0; r < 4; ++r) {
        float bb = bias[ocbase + wr + mi * 16 + lhi * 4 + r];
#pragma unroll
        for (int ni = 0; ni < 4; ++ni) acc[mi][ni][r] += bb;
      }
#pragma unroll
    for (int g = 0; g < 2; ++g) {
#pragma unroll
      for (int ni = 0; ni < 4; ++ni) {
        float m = -1e30f;
#pragma unroll
        for (int mi = 2 * g; mi < 2 * g + 2; ++mi)
#pragma unroll
          for (int r = 0; r < 4; ++r) m = fmaxf(m, acc[mi][ni][r]);
        m = fmaxf(m, __shfl_xor(m, 16));
        m = fmaxf(m, __shfl_xor(m, 32));
        float s = 0.f;
#pragma unroll
        for (int mi = 2 * g; mi < 2 * g + 2; ++mi)
#pragma unroll
          for (int r = 0; r < 4; ++r) {
            float e = __expf(acc[mi][ni][r] - m);
            acc[mi][ni][r] = e;
            s += e;
          }
        s += __shfl_xor(s, 16);
        s += __shfl_xor(s, 32);
        float inv = 1.f / s;
#pragma unroll
        for (int mi = 2 * g; mi < 2 * g + 2; ++mi)
#pragma unroll
          for (int r = 0; r < 4; ++r) acc[mi][ni][r] *= inv;
      }
    }
    unsigned short* Co2 = smem;
#pragma unroll
    for (int mi = 0; mi < 4; ++mi)
#pragma unroll
      for (int ni = 0; ni < 4; ++ni) {
        int col = wc + ni * 16 + llo;
#pragma unroll
        for (int r = 0; r < 4; ++r) {
          int row = wr + mi * 16 + lhi * 4 + r;
          Co2[col * 136 + row] = f2b(acc[mi][ni][r]);
        }
      }
    __syncthreads();
    unsigned short* dst = qsmT + ((size_t)n * HWD + l0) * CD + ocbase;
#pragma unroll
    for (int i = 0; i < 8; ++i) {
      int e = t + i * 256;
      int l = e >> 4, c8 = (e & 15) * 8;
      *(short8*)(dst + (size_t)l * CD + c8) = *(const short8*)(Co2 + l * 136 + c8);
    }
  } else {
    // keys: store exp(k+bias); values: store k+bias.
    unsigned short* Co = smem;
#pragma unroll
    for (int mi = 0; mi < 4; ++mi)
#pragma unroll
      for (int ni = 0; ni < 4; ++ni) {
        int col = wc + ni * 16 + llo;
#pragma unroll
        for (int r = 0; r < 4; ++r) {
          int row = wr + mi * 16 + lhi * 4 + r;
          float val = acc[mi][ni][r] + bias[ocbase + row];
          if (wsel == 0) val = __expf(val);
          Co[row * 136 + col] = f2b(val);
        }
      }
    __syncthreads();
    unsigned short* dst = ((wsel == 0) ? ekeys : vals)
                          + ((size_t)(n * CD + ocbase)) * HWD + l0;
#pragma unroll
    for (int i = 0; i < 8; ++i) {
      int e = t + i * 256;
      int row = e >> 4, c8 = (e & 15) * 8;
      *(short8*)(dst + (size_t)row * HWD + c8) = *(const short8*)(Co + row * 136 + c8);
    }

    if (wsel == 0) {
      // ---- per-row partial sums from Co (acc dead; reads only) ----
      int row = t >> 1, half = t & 1;
      float s = 0.f;
#pragma unroll
      for (int j = 0; j < 8; ++j) {
        const short8 u = *(const short8*)(Co + row * 136 + half * 64 + j * 8);
#pragma unroll
        for (int k = 0; k < 8; ++k) s += b2f((unsigned short)u[k]);
      }
      s += __shfl_xor(s, 1);
      if (!half) stats2d[(size_t)lt * 4096 + n * CD + ocbase + row] = s;
    }
  }
}

// ---------------------------------------------------------------------------
// ctx[n,h] (32x32) = E @ V^T UNNORMALIZED (pure streaming; 1/rowsum applied
// in proj). 2-way hf split (R17-verified).
// ---------------------------------------------------------------------------
__global__ __launch_bounds__(256)
void ctx_kernel(const unsigned short* __restrict__ ekeys,
                const unsigned short* __restrict__ vals,
                float* __restrict__ ctxp)       // [2][128][32][32]
{
  __shared__ float Cs[4][32][33];
  const int hf = blockIdx.x;          // 0,1
  const int nh = blockIdx.y;          // 0..127
  const int n = nh >> 3, h = nh & 7;
  const int t = threadIdx.x, w = t >> 6, lane = t & 63;
  const int lhi = lane >> 4, llo = lane & 15;
  const int lbase = hf * 2048 + w * 512;

  const unsigned short* kr = ekeys + (size_t)(n * CD + h * 32) * HWD;
  const unsigned short* vr = vals + (size_t)(n * CD + h * 32) * HWD;

  f32x4 acc[2][2] = {};
  for (int ks = 0; ks < 16; ++ks) {
    const int loff = lbase + ks * 32 + lhi * 8;
    short8 a[2], b[2];
#pragma unroll
    for (int mi = 0; mi < 2; ++mi)
      a[mi] = *(const short8*)(kr + (size_t)(mi * 16 + llo) * HWD + loff);
#pragma unroll
    for (int ni = 0; ni < 2; ++ni)
      b[ni] = *(const short8*)(vr + (size_t)(ni * 16 + llo) * HWD + loff);
    acc[0][0] = __builtin_amdgcn_mfma_f32_16x16x32_bf16(a[0], b[0], acc[0][0], 0, 0, 0);
    acc[0][1] = __builtin_amdgcn_mfma_f32_16x16x32_bf16(a[0], b[1], acc[0][1], 0, 0, 0);
    acc[1][0] = __builtin_amdgcn_mfma_f32_16x16x32_bf16(a[1], b[0], acc[1][0], 0, 0, 0);
    acc[1][1] = __builtin_amdgcn_mfma_f32_16x16x32_bf16(a[1], b[1], acc[1][1], 0, 0, 0);
  }

#pragma unroll
  for (int mi = 0; mi < 2; ++mi)
#pragma unroll
    for (int ni = 0; ni < 2; ++ni)
#pragma unroll
      for (int r = 0; r < 4; ++r)
        Cs[w][mi * 16 + lhi * 4 + r][ni * 16 + llo] = acc[mi][ni][r];
  __syncthreads();
#pragma unroll
  for (int i = 0; i < 4; ++i) {
    int e = t + i * 256;
    int kc = e >> 5, vc = e & 31;
    float sum = Cs[0][kc][vc] + Cs[1][kc][vc] + Cs[2][kc][vc] + Cs[3][kc][vc];
    ctxp[((size_t)hf * 128 + nh) * 1024 + e] = sum;
  }
}

// ---------------------------------------------------------------------------
// proj: sums 2 ctx partials, applies inv[kc] = 1/(sum of 32 stats2d
// partials), then M_n[o][h*32+kc] = sum_vc Wr[o][h*32+vc]*ctx[kc][vc], bf16.
// ---------------------------------------------------------------------------
__global__ __launch_bounds__(256)
void proj_kernel(const float* __restrict__ ctxp, const float* __restrict__ Wr,
                 const float* __restrict__ stats2d,
                 unsigned short* __restrict__ M)
{
  __shared__ float cs[32][33];
  __shared__ float invs[32];
  const int nh = blockIdx.x;
  const int n = nh >> 3, h = nh & 7;
  const int t = threadIdx.x;

  if (t < 32) {
    int grow = n * CD + h * 32 + t;
    float s = 0.f;
#pragma unroll
    for (int p = 0; p < 32; ++p) s += stats2d[(size_t)p * 4096 + grow];
    invs[t] = 1.f / s;
  }
  __syncthreads();

#pragma unroll
  for (int i = 0; i < 4; ++i) {
    int e = t + i * 256;
    float s = ctxp[(size_t)nh * 1024 + e] + ctxp[((size_t)128 + nh) * 1024 + e];
    cs[e >> 5][e & 31] = s * invs[e >> 5];
  }
  __syncthreads();
  float wreg[32];
  const float* wp = Wr + (size_t)t * 256 + h * 32;
#pragma unroll
  for (int i = 0; i < 8; ++i) {
    f32x4 v = *(const f32x4*)(wp + i * 4);
    wreg[i * 4] = v.x; wreg[i * 4 + 1] = v.y; wreg[i * 4 + 2] = v.z; wreg[i * 4 + 3] = v.w;
  }
  unsigned short o16[32];
#pragma unroll
  for (int kc = 0; kc < 32; ++kc) {
    float s = 0.f;
#pragma unroll
    for (int vv = 0; vv < 32; ++vv) s += wreg[vv] * cs[kc][vv];
    o16[kc] = f2b(s);
  }
  unsigned short* mp = M + (size_t)(n * CD + t) * 256 + h * 32;
#pragma unroll
  for (int i = 0; i < 8; ++i) {
    unsigned int lo = (unsigned int)o16[i * 4]     | ((unsigned int)o16[i * 4 + 1] << 16);
    unsigned int hi = (unsigned int)o16[i * 4 + 2] | ((unsigned int)o16[i * 4 + 3] << 16);
    *(uint2*)(mp + i * 4) = make_uint2(lo, hi);
  }
}

// ---------------------------------------------------------------------------
// out: kqv-template GEMM (128x128 tile, BK=32 NBUF=2, counted-vmcnt,
// 16KB LDS -> 4 blocks/CU). A = M_n, B = qsmT. Epilogue: bias + residual.
// ---------------------------------------------------------------------------
__global__ __launch_bounds__(256, 4)
void out_kernel(const unsigned short* __restrict__ M,
                const unsigned short* __restrict__ qsmT,
                const float* __restrict__ br,
                const float* __restrict__ x,
                float* __restrict__ out)
{
  __shared__ __align__(16) unsigned short smem[16384];

  const int t  = threadIdx.x;
  const int lt = blockIdx.x;        // 0..31
  const int mt = blockIdx.y;        // 0..1
  const int n  = blockIdx.z;
  const int l0 = lt * 128, m0 = mt * 128;

  const unsigned short* Ag  = M + (size_t)n * CD * 256;
  const unsigned short* Btn = qsmT + (size_t)n * HWD * CD;

  const int w = t >> 6, lane = t & 63;
  const int wr = (w >> 1) * 64, wc = (w & 1) * 64;
  const int lhi = lane >> 4, llo = lane & 15;

  f32x4 acc[4][4] = {};

  auto stage = [&](int buf, int ks) {
    unsigned short* As = smem + buf * 8192;
    unsigned short* Bs = As + 4096;
    const int k0 = ks * 32;
#pragma unroll
    for (int i = 0; i < 2; ++i) {
      int s   = t + i * 256;
      int row = s >> 2;
      int src = (((s ^ row) & 3)) << 3;
      gload16(Ag  + (size_t)(m0 + row) * CD + k0 + src, As + s * 8);
      gload16(Btn + (size_t)(l0 + row) * CD + k0 + src, Bs + s * 8);
    }
  };

  stage(0, 0);
  stage(1, 1);
#pragma unroll
  for (int ks = 0; ks < 8; ++ks) {
    if (ks < 7) asm volatile("s_waitcnt vmcnt(4)" ::: "memory");
    else        asm volatile("s_waitcnt vmcnt(0)" ::: "memory");
    asm volatile("s_barrier" ::: "memory");

    const unsigned short* As = smem + (ks & 1) * 8192;
    const unsigned short* Bs = As + 4096;
    const int slot = (lhi ^ (llo & 3)) * 8;
    short8 a[4], b[4];
#pragma unroll
    for (int mi = 0; mi < 4; ++mi)
      a[mi] = *(const short8*)(As + (wr + mi * 16 + llo) * 32 + slot);
#pragma unroll
    for (int ni = 0; ni < 4; ++ni)
      b[ni] = *(const short8*)(Bs + (wc + ni * 16 + llo) * 32 + slot);

    asm volatile("s_waitcnt lgkmcnt(0)" ::: "memory");
    asm volatile("s_barrier" ::: "memory");

    if (ks < 6) stage(ks & 1, ks + 2);

#pragma unroll
    for (int mi = 0; mi < 4; ++mi)
#pragma unroll
      for (int ni = 0; ni < 4; ++ni)
        acc[mi][ni] = __builtin_amdgcn_mfma_f32_16x16x32_bf16(a[mi], b[ni], acc[mi][ni], 0, 0, 0);
  }

  // epilogue: bias + residual, direct fp32 stores
  const float* xn = x + (size_t)n * CD * HWD;
  float* on = out + (size_t)n * CD * HWD;
#pragma unroll
  for (int mi = 0; mi < 4; ++mi)
#pragma unroll
    for (int r = 0; r < 4; ++r) {
      int row = m0 + wr + mi * 16 + lhi * 4 + r;
      float bb = br[row];
#pragma unroll
      for (int ni = 0; ni < 4; ++ni) {
        int col = l0 + wc + ni * 16 + llo;
        size_t off = (size_t)row * HWD + col;
        on[off] = acc[mi][ni][r] + bb + xn[off];
      }
    }
}

// ---------------------------------------------------------------------------
extern "C" void kernel_launch(void* const* d_in, const int* in_sizes, int n_in,
                              void* d_out, int out_size, void* d_ws, size_t ws_size,
                              hipStream_t stream) {
  const float* x  = (const float*)d_in[0];
  const float* Wk = (const float*)d_in[1];
  const float* bk = (const float*)d_in[2];
  const float* Wq = (const float*)d_in[3];
  const float* bq = (const float*)d_in[4];
  const float* Wv = (const float*)d_in[5];
  const float* bv = (const float*)d_in[6];
  const float* Wr = (const float*)d_in[7];
  const float* br = (const float*)d_in[8];
  float* out = (float*)d_out;

  char* ws = (char*)d_ws;
  // ws layout (bytes): ekeys 32M | vals 32M | qsmT 32M | stats2d 512K | M 2M | Wc 384K
  unsigned short* ekeys = (unsigned short*)(ws);
  unsigned short* vals  = (unsigned short*)(ws + 33554432);
  unsigned short* qsmT  = (unsigned short*)(ws + 67108864);
  float* stats2d        = (float*)(ws + 100663296);
  unsigned short* M     = (unsigned short*)(ws + 101744640);
  unsigned short* Wc    = (unsigned short*)(ws + 103841792);
  // d_out scratch: xT bf16 (32MB) at offset 0 (dead before out_kernel writes),
  // ctx partials f32 [2][128][1024] (1MB) at +32MB (consumed by proj first).
  unsigned short* xT    = (unsigned short*)d_out;
  float* ctxp           = (float*)((char*)d_out + 33554432);

  hipLaunchKernelGGL(prep_kernel, dim3(192), dim3(256), 0, stream, Wk, Wq, Wv, Wc);
  hipLaunchKernelGGL(xt_kernel, dim3(64, 4, NB), dim3(256), 0, stream, x, xT);
  hipLaunchKernelGGL(kqv_kernel, dim3(32, 6, NB), dim3(256), 0, stream,
                     Wc, xT, bk, bq, bv, ekeys, qsmT, vals, stats2d);
  hipLaunchKernelGGL(ctx_kernel, dim3(2, 128), dim3(256), 0, stream,
                     ekeys, vals, ctxp);
  hipLaunchKernelGGL(proj_kernel, dim3(128), dim3(256), 0, stream,
                     ctxp, Wr, stats2d, M);
  hipLaunchKernelGGL(out_kernel, dim3(32, 2, NB), dim3(256), 0, stream,
                     M, qsmT, br, x, out);
}

// Round 20
// 122.487 us; speedup vs baseline: 1.0232x; 1.0217x over previous
//
#include <hip/hip_runtime.h>

#define NB   16
#define CD   256
#define HWD  4096

typedef __attribute__((ext_vector_type(8))) short short8;
typedef __attribute__((ext_vector_type(4))) float f32x4;

static __device__ __forceinline__ float b2f(unsigned short u) {
  union { unsigned int i; float f; } x; x.i = ((unsigned int)u) << 16; return x.f;
}
static __device__ __forceinline__ unsigned short f2b(float f) {
  union { float f; unsigned int i; } x; x.f = f;
  return (unsigned short)((x.i + 0x7fffu + ((x.i >> 16) & 1u)) >> 16);
}

static __device__ __forceinline__ void gload16(const void* g, const unsigned short* l) {
  __builtin_amdgcn_global_load_lds(
      (const __attribute__((address_space(1))) void*)g,
      (__attribute__((address_space(3))) void*)l, 16, 0, 0);
}

// ---------------------------------------------------------------------------
// prep: Wk|Wq|Wv (each 256x256 f32) -> Wc bf16 [768][256]
// ---------------------------------------------------------------------------
__global__ __launch_bounds__(256)
void prep_kernel(const float* __restrict__ Wk, const float* __restrict__ Wq,
                 const float* __restrict__ Wv, unsigned short* __restrict__ Wc)
{
  int e4 = blockIdx.x * 256 + threadIdx.x;
  int base = e4 * 4;
  int w = base >> 16, off = base & 65535;
  const float* W = (w == 0) ? Wk : (w == 1) ? Wq : Wv;
  f32x4 v = *(const f32x4*)(W + off);
  unsigned int lo = (unsigned int)f2b(v.x) | ((unsigned int)f2b(v.y) << 16);
  unsigned int hi = (unsigned int)f2b(v.z) | ((unsigned int)f2b(v.w) << 16);
  *(uint2*)(Wc + base) = make_uint2(lo, hi);
}

// ---------------------------------------------------------------------------
// xT: x [n][256][4096] f32 -> xT [n][4096][256] bf16  (tile transpose)
// ---------------------------------------------------------------------------
__global__ __launch_bounds__(256)
void xt_kernel(const float* __restrict__ x, unsigned short* __restrict__ xT)
{
  __shared__ __align__(16) unsigned short T[64 * 80];
  const int t = threadIdx.x;
  const int l0 = blockIdx.x * 64, c0 = blockIdx.y * 64, n = blockIdx.z;
  const float* xn = x + (size_t)n * CD * HWD;
#pragma unroll
  for (int i = 0; i < 4; ++i) {
    int idx = t + i * 256;
    int c = idx >> 4, l4 = (idx & 15) * 4;
    f32x4 v = *(const f32x4*)(xn + (size_t)(c0 + c) * HWD + l0 + l4);
    T[(l4 + 0) * 80 + c] = f2b(v.x);
    T[(l4 + 1) * 80 + c] = f2b(v.y);
    T[(l4 + 2) * 80 + c] = f2b(v.z);
    T[(l4 + 3) * 80 + c] = f2b(v.w);
  }
  __syncthreads();
  unsigned short* dst = xT + ((size_t)n * HWD + l0) * CD + c0;
#pragma unroll
  for (int i = 0; i < 2; ++i) {
    int e = t + i * 256;
    int lr = e >> 3, c8 = (e & 7) * 8;
    *(short8*)(dst + (size_t)lr * CD + c8) = *(const short8*)(T + lr * 80 + c8);
  }
}

// ---------------------------------------------------------------------------
// kqv: 128x128 tile, BK=32 dbuf (NBUF=2), depth-2 counted-vmcnt pipeline
// (R11/R13-verified). Keys stored as exp(keys+bias) + per-row partial sums
// (from the Co LDS buffer, AFTER acc is dead) to stats2d[32][4096].
// Queries: in-register head-group(32) softmax, stored TRANSPOSED qsmT[l][c].
// (R17 verbatim)
// ---------------------------------------------------------------------------
__global__ __launch_bounds__(256, 4)
void kqv_kernel(const unsigned short* __restrict__ Wc,
                const unsigned short* __restrict__ xT,
                const float* __restrict__ bk, const float* __restrict__ bq,
                const float* __restrict__ bv,
                unsigned short* __restrict__ ekeys,
                unsigned short* __restrict__ qsmT,
                unsigned short* __restrict__ vals,
                float* __restrict__ stats2d)
{
  __shared__ __align__(16) unsigned short smem[17408];

  const int t  = threadIdx.x;
  const int lt = blockIdx.x;        // 0..31
  const int mt = blockIdx.y;        // 0..5
  const int n  = blockIdx.z;
  const int l0 = lt * 128;
  const int m0 = mt * 128;
  const int wsel = m0 >> 8;         // 0 keys, 1 queries, 2 values
  const int ocbase = m0 & 255;

  const unsigned short* Ag  = Wc;
  const unsigned short* Btn = xT + (size_t)n * HWD * CD;

  const int w = t >> 6, lane = t & 63;
  const int wr = (w >> 1) * 64, wc = (w & 1) * 64;
  const int lhi = lane >> 4, llo = lane & 15;

  f32x4 acc[4][4] = {};

  auto stage = [&](int buf, int ks) {
    unsigned short* As = smem + buf * 8192;
    unsigned short* Bs = As + 4096;
    const int k0 = ks * 32;
#pragma unroll
    for (int i = 0; i < 2; ++i) {
      int s   = t + i * 256;
      int row = s >> 2;
      int src = (((s ^ row) & 3)) << 3;
      gload16(Ag  + (size_t)(m0 + row) * CD + k0 + src, As + s * 8);
      gload16(Btn + (size_t)(l0 + row) * CD + k0 + src, Bs + s * 8);
    }
  };

  stage(0, 0);
  stage(1, 1);                      // 8 loads outstanding
#pragma unroll
  for (int ks = 0; ks < 8; ++ks) {
    if (ks < 7) asm volatile("s_waitcnt vmcnt(4)" ::: "memory");
    else        asm volatile("s_waitcnt vmcnt(0)" ::: "memory");
    asm volatile("s_barrier" ::: "memory");        // cur buf landed everywhere

    const unsigned short* As = smem + (ks & 1) * 8192;
    const unsigned short* Bs = As + 4096;
    const int slot = (lhi ^ (llo & 3)) * 8;
    short8 a[4], b[4];
#pragma unroll
    for (int mi = 0; mi < 4; ++mi)
      a[mi] = *(const short8*)(As + (wr + mi * 16 + llo) * 32 + slot);
#pragma unroll
    for (int ni = 0; ni < 4; ++ni)
      b[ni] = *(const short8*)(Bs + (wc + ni * 16 + llo) * 32 + slot);

    asm volatile("s_waitcnt lgkmcnt(0)" ::: "memory");  // reads complete
    asm volatile("s_barrier" ::: "memory");             // all waves done reading

    if (ks < 6) stage(ks & 1, ks + 2);   // overwrite cur; back to 8 in flight

#pragma unroll
    for (int mi = 0; mi < 4; ++mi)
#pragma unroll
      for (int ni = 0; ni < 4; ++ni)
        acc[mi][ni] = __builtin_amdgcn_mfma_f32_16x16x32_bf16(a[mi], b[ni], acc[mi][ni], 0, 0, 0);
  }

  const float* bias = (wsel == 0) ? bk : (wsel == 1) ? bq : bv;

  if (wsel == 1) {
#pragma unroll
    for (int mi = 0; mi < 4; ++mi)
#pragma unroll
      for (int r = 0; r < 4; ++r) {
        float bb = bias[ocbase + wr + mi * 16 + lhi * 4 + r];
#pragma unroll
        for (int ni = 0; ni < 4; ++ni) acc[mi][ni][r] += bb;
      }
#pragma unroll
    for (int g = 0; g < 2; ++g) {
#pragma unroll
      for (int ni = 0; ni < 4; ++ni) {
        float m = -1e30f;
#pragma unroll
        for (int mi = 2 * g; mi < 2 * g + 2; ++mi)
#pragma unroll
          for (int r = 0; r < 4; ++r) m = fmaxf(m, acc[mi][ni][r]);
        m = fmaxf(m, __shfl_xor(m, 16));
        m = fmaxf(m, __shfl_xor(m, 32));
        float s = 0.f;
#pragma unroll
        for (int mi = 2 * g; mi < 2 * g + 2; ++mi)
#pragma unroll
          for (int r = 0; r < 4; ++r) {
            float e = __expf(acc[mi][ni][r] - m);
            acc[mi][ni][r] = e;
            s += e;
          }
        s += __shfl_xor(s, 16);
        s += __shfl_xor(s, 32);
        float inv = 1.f / s;
#pragma unroll
        for (int mi = 2 * g; mi < 2 * g + 2; ++mi)
#pragma unroll
          for (int r = 0; r < 4; ++r) acc[mi][ni][r] *= inv;
      }
    }
    unsigned short* Co2 = smem;
#pragma unroll
    for (int mi = 0; mi < 4; ++mi)
#pragma unroll
      for (int ni = 0; ni < 4; ++ni) {
        int col = wc + ni * 16 + llo;
#pragma unroll
        for (int r = 0; r < 4; ++r) {
          int row = wr + mi * 16 + lhi * 4 + r;
          Co2[col * 136 + row] = f2b(acc[mi][ni][r]);
        }
      }
    __syncthreads();
    unsigned short* dst = qsmT + ((size_t)n * HWD + l0) * CD + ocbase;
#pragma unroll
    for (int i = 0; i < 8; ++i) {
      int e = t + i * 256;
      int l = e >> 4, c8 = (e & 15) * 8;
      *(short8*)(dst + (size_t)l * CD + c8) = *(const short8*)(Co2 + l * 136 + c8);
    }
  } else {
    // keys: store exp(k+bias); values: store k+bias.
    unsigned short* Co = smem;
#pragma unroll
    for (int mi = 0; mi < 4; ++mi)
#pragma unroll
      for (int ni = 0; ni < 4; ++ni) {
        int col = wc + ni * 16 + llo;
#pragma unroll
        for (int r = 0; r < 4; ++r) {
          int row = wr + mi * 16 + lhi * 4 + r;
          float val = acc[mi][ni][r] + bias[ocbase + row];
          if (wsel == 0) val = __expf(val);
          Co[row * 136 + col] = f2b(val);
        }
      }
    __syncthreads();
    unsigned short* dst = ((wsel == 0) ? ekeys : vals)
                          + ((size_t)(n * CD + ocbase)) * HWD + l0;
#pragma unroll
    for (int i = 0; i < 8; ++i) {
      int e = t + i * 256;
      int row = e >> 4, c8 = (e & 15) * 8;
      *(short8*)(dst + (size_t)row * HWD + c8) = *(const short8*)(Co + row * 136 + c8);
    }

    if (wsel == 0) {
      // ---- per-row partial sums from Co (acc dead; reads only) ----
      int row = t >> 1, half = t & 1;
      float s = 0.f;
#pragma unroll
      for (int j = 0; j < 8; ++j) {
        const short8 u = *(const short8*)(Co + row * 136 + half * 64 + j * 8);
#pragma unroll
        for (int k = 0; k < 8; ++k) s += b2f((unsigned short)u[k]);
      }
      s += __shfl_xor(s, 1);
      if (!half) stats2d[(size_t)lt * 4096 + n * CD + ocbase + row] = s;
    }
  }
}

// ---------------------------------------------------------------------------
// ctx[n,h] (32x32) = E @ V^T UNNORMALIZED (pure streaming; 1/rowsum applied
// in proj). 2-way hf split (R17-verified).
// ---------------------------------------------------------------------------
__global__ __launch_bounds__(256)
void ctx_kernel(const unsigned short* __restrict__ ekeys,
                const unsigned short* __restrict__ vals,
                float* __restrict__ ctxp)       // [2][128][32][32]
{
  __shared__ float Cs[4][32][33];
  const int hf = blockIdx.x;          // 0,1
  const int nh = blockIdx.y;          // 0..127
  const int n = nh >> 3, h = nh & 7;
  const int t = threadIdx.x, w = t >> 6, lane = t & 63;
  const int lhi = lane >> 4, llo = lane & 15;
  const int lbase = hf * 2048 + w * 512;

  const unsigned short* kr = ekeys + (size_t)(n * CD + h * 32) * HWD;
  const unsigned short* vr = vals + (size_t)(n * CD + h * 32) * HWD;

  f32x4 acc[2][2] = {};
  for (int ks = 0; ks < 16; ++ks) {
    const int loff = lbase + ks * 32 + lhi * 8;
    short8 a[2], b[2];
#pragma unroll
    for (int mi = 0; mi < 2; ++mi)
      a[mi] = *(const short8*)(kr + (size_t)(mi * 16 + llo) * HWD + loff);
#pragma unroll
    for (int ni = 0; ni < 2; ++ni)
      b[ni] = *(const short8*)(vr + (size_t)(ni * 16 + llo) * HWD + loff);
    acc[0][0] = __builtin_amdgcn_mfma_f32_16x16x32_bf16(a[0], b[0], acc[0][0], 0, 0, 0);
    acc[0][1] = __builtin_amdgcn_mfma_f32_16x16x32_bf16(a[0], b[1], acc[0][1], 0, 0, 0);
    acc[1][0] = __builtin_amdgcn_mfma_f32_16x16x32_bf16(a[1], b[0], acc[1][0], 0, 0, 0);
    acc[1][1] = __builtin_amdgcn_mfma_f32_16x16x32_bf16(a[1], b[1], acc[1][1], 0, 0, 0);
  }

#pragma unroll
  for (int mi = 0; mi < 2; ++mi)
#pragma unroll
    for (int ni = 0; ni < 2; ++ni)
#pragma unroll
      for (int r = 0; r < 4; ++r)
        Cs[w][mi * 16 + lhi * 4 + r][ni * 16 + llo] = acc[mi][ni][r];
  __syncthreads();
#pragma unroll
  for (int i = 0; i < 4; ++i) {
    int e = t + i * 256;
    int kc = e >> 5, vc = e & 31;
    float sum = Cs[0][kc][vc] + Cs[1][kc][vc] + Cs[2][kc][vc] + Cs[3][kc][vc];
    ctxp[((size_t)hf * 128 + nh) * 1024 + e] = sum;
  }
}

// ---------------------------------------------------------------------------
// proj: sums 2 ctx partials, applies inv[kc] = 1/(sum of 32 stats2d
// partials), then M_n[o][h*32+kc] = sum_vc Wr[o][h*32+vc]*ctx[kc][vc], bf16.
// ---------------------------------------------------------------------------
__global__ __launch_bounds__(256)
void proj_kernel(const float* __restrict__ ctxp, const float* __restrict__ Wr,
                 const float* __restrict__ stats2d,
                 unsigned short* __restrict__ M)
{
  __shared__ float cs[32][33];
  __shared__ float invs[32];
  const int nh = blockIdx.x;
  const int n = nh >> 3, h = nh & 7;
  const int t = threadIdx.x;

  if (t < 32) {
    int grow = n * CD + h * 32 + t;
    float s = 0.f;
#pragma unroll
    for (int p = 0; p < 32; ++p) s += stats2d[(size_t)p * 4096 + grow];
    invs[t] = 1.f / s;
  }
  __syncthreads();

#pragma unroll
  for (int i = 0; i < 4; ++i) {
    int e = t + i * 256;
    float s = ctxp[(size_t)nh * 1024 + e] + ctxp[((size_t)128 + nh) * 1024 + e];
    cs[e >> 5][e & 31] = s * invs[e >> 5];
  }
  __syncthreads();
  float wreg[32];
  const float* wp = Wr + (size_t)t * 256 + h * 32;
#pragma unroll
  for (int i = 0; i < 8; ++i) {
    f32x4 v = *(const f32x4*)(wp + i * 4);
    wreg[i * 4] = v.x; wreg[i * 4 + 1] = v.y; wreg[i * 4 + 2] = v.z; wreg[i * 4 + 3] = v.w;
  }
  unsigned short o16[32];
#pragma unroll
  for (int kc = 0; kc < 32; ++kc) {
    float s = 0.f;
#pragma unroll
    for (int vv = 0; vv < 32; ++vv) s += wreg[vv] * cs[kc][vv];
    o16[kc] = f2b(s);
  }
  unsigned short* mp = M + (size_t)(n * CD + t) * 256 + h * 32;
#pragma unroll
  for (int i = 0; i < 8; ++i) {
    unsigned int lo = (unsigned int)o16[i * 4]     | ((unsigned int)o16[i * 4 + 1] << 16);
    unsigned int hi = (unsigned int)o16[i * 4 + 2] | ((unsigned int)o16[i * 4 + 3] << 16);
    *(uint2*)(mp + i * 4) = make_uint2(lo, hi);
  }
}

// ---------------------------------------------------------------------------
// out: 64x64 tile, BOTH panels (M rows, qsmT rows; K=256) LDS-resident via
// one gload16 stage; barrier-free K-loop (R13/R17 verbatim). Epilogue: bias +
// residual, fp32 direct.
// ---------------------------------------------------------------------------
__global__ __launch_bounds__(256, 2)
void out_kernel(const unsigned short* __restrict__ M,
                const unsigned short* __restrict__ qsmT,
                const float* __restrict__ br,
                const float* __restrict__ x,
                float* __restrict__ out)
{
  __shared__ __align__(16) unsigned short smem[32768];  // As 64x256 | Bs 64x256
  unsigned short* As = smem;
  unsigned short* Bs = smem + 16384;

  const int t  = threadIdx.x;
  const int lt = blockIdx.x;        // 0..63
  const int mt = blockIdx.y;        // 0..3
  const int n  = blockIdx.z;
  const int l0 = lt * 64, m0 = mt * 64;

  const unsigned short* Ag  = M + (size_t)n * CD * 256;
  const unsigned short* Btn = qsmT + (size_t)n * HWD * CD;

  const int wid = t >> 6, lane = t & 63;
  const int wr = (wid >> 1) * 32, wc = (wid & 1) * 32;
  const int lhi = lane >> 4, llo = lane & 15;

#pragma unroll
  for (int i = 0; i < 8; ++i) {
    int s = t + i * 256;            // 0..2047
    int R = s >> 5, sl = s & 31;
    int srcsl = (sl & 24) | ((sl ^ R) & 7);
    gload16(Ag  + (size_t)(m0 + R) * CD + srcsl * 8, As + s * 8);
    gload16(Btn + (size_t)(l0 + R) * CD + srcsl * 8, Bs + s * 8);
  }
  __syncthreads();

  f32x4 acc[2][2] = {};
#pragma unroll
  for (int ks = 0; ks < 8; ++ks) {
    int jg = ks * 4 + lhi;          // k-slot 0..31
    short8 a[2], b[2];
#pragma unroll
    for (int mi = 0; mi < 2; ++mi) {
      int R = wr + mi * 16 + llo;
      int pj = (jg & 24) | ((jg ^ (R & 7)) & 7);
      a[mi] = *(const short8*)(As + R * 256 + pj * 8);
    }
#pragma unroll
    for (int ni = 0; ni < 2; ++ni) {
      int l = wc + ni * 16 + llo;
      int pj = (jg & 24) | ((jg ^ (l & 7)) & 7);
      b[ni] = *(const short8*)(Bs + l * 256 + pj * 8);
    }
#pragma unroll
    for (int mi = 0; mi < 2; ++mi)
#pragma unroll
      for (int ni = 0; ni < 2; ++ni)
        acc[mi][ni] = __builtin_amdgcn_mfma_f32_16x16x32_bf16(a[mi], b[ni], acc[mi][ni], 0, 0, 0);
  }

  const float* xn = x + (size_t)n * CD * HWD;
  float* on = out + (size_t)n * CD * HWD;
#pragma unroll
  for (int mi = 0; mi < 2; ++mi)
#pragma unroll
    for (int r = 0; r < 4; ++r) {
      int row = m0 + wr + mi * 16 + lhi * 4 + r;
      float bb = br[row];
#pragma unroll
      for (int ni = 0; ni < 2; ++ni) {
        int col = l0 + wc + ni * 16 + llo;
        size_t off = (size_t)row * HWD + col;
        on[off] = acc[mi][ni][r] + bb + xn[off];
      }
    }
}

// ---------------------------------------------------------------------------
extern "C" void kernel_launch(void* const* d_in, const int* in_sizes, int n_in,
                              void* d_out, int out_size, void* d_ws, size_t ws_size,
                              hipStream_t stream) {
  const float* x  = (const float*)d_in[0];
  const float* Wk = (const float*)d_in[1];
  const float* bk = (const float*)d_in[2];
  const float* Wq = (const float*)d_in[3];
  const float* bq = (const float*)d_in[4];
  const float* Wv = (const float*)d_in[5];
  const float* bv = (const float*)d_in[6];
  const float* Wr = (const float*)d_in[7];
  const float* br = (const float*)d_in[8];
  float* out = (float*)d_out;

  char* ws = (char*)d_ws;
  // ws layout (bytes): ekeys 32M | vals 32M | qsmT 32M | stats2d 512K | M 2M | Wc 384K
  unsigned short* ekeys = (unsigned short*)(ws);
  unsigned short* vals  = (unsigned short*)(ws + 33554432);
  unsigned short* qsmT  = (unsigned short*)(ws + 67108864);
  float* stats2d        = (float*)(ws + 100663296);
  unsigned short* M     = (unsigned short*)(ws + 101744640);
  unsigned short* Wc    = (unsigned short*)(ws + 103841792);
  // d_out scratch: xT bf16 (32MB) at offset 0 (dead before out_kernel writes),
  // ctx partials f32 [2][128][1024] (1MB) at +32MB (consumed by proj first).
  unsigned short* xT    = (unsigned short*)d_out;
  float* ctxp           = (float*)((char*)d_out + 33554432);

  hipLaunchKernelGGL(prep_kernel, dim3(192), dim3(256), 0, stream, Wk, Wq, Wv, Wc);
  hipLaunchKernelGGL(xt_kernel, dim3(64, 4, NB), dim3(256), 0, stream, x, xT);
  hipLaunchKernelGGL(kqv_kernel, dim3(32, 6, NB), dim3(256), 0, stream,
                     Wc, xT, bk, bq, bv, ekeys, qsmT, vals, stats2d);
  hipLaunchKernelGGL(ctx_kernel, dim3(2, 128), dim3(256), 0, stream,
                     ekeys, vals, ctxp);
  hipLaunchKernelGGL(proj_kernel, dim3(128), dim3(256), 0, stream,
                     ctxp, Wr, stats2d, M);
  hipLaunchKernelGGL(out_kernel, dim3(64, 4, NB), dim3(256), 0, stream,
                     M, qsmT, br, x, out);
}